// Round 2
// baseline (640.374 us; speedup 1.0000x reference)
//
#include <hip/hip_runtime.h>

// IF (integrate-and-fire) forward, T=4 timesteps, B=8, FEAT=1024*3072, fp32.
//
// x / out: [T*B, 1024, 3072] flat fp32; thresh2 / dtmem: [1024*3072].
// Recurrence is only over t (T=4); b is parallel. One thread owns TWO float4
// feature chunks (f0, f0+256) for one batch b. All 8 x-loads are issued
// explicitly BEFORE the t-loop: 8 NT loads in flight hide ~900-cycle HBM
// latency; dependency chain per t is add -> cmp/sel -> store -> sub.
//
// XCD-aware block swizzle: b = bid / fchunks, fchunk = bid % fchunks. Blocks
// sharing a param line have bids congruent mod 8 (fchunks = 1536 = 0 mod 8),
// so round-robin workgroup dispatch lands them on the SAME XCD -> thresh2 /
// dtmem re-reads hit the private L2 instead of bouncing to L3.
//
// SINGLE-VARIABLE CHANGE UNDER TEST (re-run; round-1 bench was an infra
// failure, no data): stores are PLAIN (L2 write-back path) instead of
// nontemporal. The harness fill kernels (plain stores) measure 6.28-6.41
// TB/s; if the nt-bit store path was throttling our 402 MB write stream,
// this recovers it. Param-eviction risk is bounded: 3.1 MB/XCD param slice
// re-fetches from the 256 MB L3, not HBM. x loads stay NT (read-once, keep
// them out of L2 so params have the best shot at staying resident).
//
// Memory-bound: ~830 MB HBM -> ~132 us floor @ 6.3 TB/s achievable.

typedef float vf4 __attribute__((ext_vector_type(4)));

constexpr int T_STEPS = 4;
constexpr int B_SZ    = 8;

__device__ __forceinline__ vf4 spike_of(vf4 m, vf4 th) {
    vf4 s;
    s.x = (m.x - th.x >= 0.0f) ? th.x : 0.0f;
    s.y = (m.y - th.y >= 0.0f) ? th.y : 0.0f;
    s.z = (m.z - th.z >= 0.0f) ? th.z : 0.0f;
    s.w = (m.w - th.w >= 0.0f) ? th.w : 0.0f;
    return s;
}

__global__ __launch_bounds__(256) void if_fwd_kernel(
    const vf4* __restrict__ x,
    const vf4* __restrict__ thresh2,
    const vf4* __restrict__ dtmem,
    vf4* __restrict__ out,
    int n4,          // feature float4 count = 786432
    int fchunks)     // n4 / 512 = 1536
{
    const int bid    = blockIdx.x;
    const int b      = bid / fchunks;            // batch index 0..7
    const int fchunk = bid - b * fchunks;

    const int f0 = fchunk * 512 + threadIdx.x;   // first chunk
    const int f1 = f0 + 256;                     // second chunk

    // params: cached reads (L2-resident thanks to XCD swizzle)
    const vf4 th0 = thresh2[f0];
    const vf4 th1 = thresh2[f1];
    vf4 m0 = dtmem[f0] * th0;                    // initial membrane: dtmem * thre
    vf4 m1 = dtmem[f1] * th1;

    const long long base = (long long)b * n4;

    // Explicitly issue ALL 8 streaming loads before any compute: maximal MLP
    // independent of how the unroller schedules the recurrence.
    vf4 xv0[T_STEPS], xv1[T_STEPS];
#pragma unroll
    for (int t = 0; t < T_STEPS; ++t) {
        const long long row = (long long)(t * B_SZ) * n4 + base;
        xv0[t] = __builtin_nontemporal_load(&x[row + f0]);
        xv1[t] = __builtin_nontemporal_load(&x[row + f1]);
    }

#pragma unroll
    for (int t = 0; t < T_STEPS; ++t) {
        const long long row = (long long)(t * B_SZ) * n4 + base;

        m0 += xv0[t];
        m1 += xv1[t];

        const vf4 s0 = spike_of(m0, th0);
        const vf4 s1 = spike_of(m1, th1);

        out[row + f0] = s0;   // plain store: L2 write-back path (fills hit 6.3 TB/s here)
        out[row + f1] = s1;

        m0 -= s0;
        m1 -= s1;
    }
}

extern "C" void kernel_launch(void* const* d_in, const int* in_sizes, int n_in,
                              void* d_out, int out_size, void* d_ws, size_t ws_size,
                              hipStream_t stream) {
    const float* x       = (const float*)d_in[0];   // [T*B*1024*3072]
    const float* thresh2 = (const float*)d_in[1];   // [1024*3072]
    const float* dtmem   = (const float*)d_in[2];   // [1024*3072]
    float* out = (float*)d_out;

    const int n  = in_sizes[1];      // 1024*3072 = 3,145,728
    const int n4 = n / 4;            // 786,432 float4 features

    const int block   = 256;
    const int fchunks = n4 / (2 * block);           // 1536 (exact)
    const int grid    = fchunks * B_SZ;             // 12,288 blocks

    if_fwd_kernel<<<grid, block, 0, stream>>>(
        (const vf4*)x, (const vf4*)thresh2, (const vf4*)dtmem,
        (vf4*)out, n4, fchunks);
}